// Round 1
// baseline (303.730 us; speedup 1.0000x reference)
//
#include <hip/hip_runtime.h>
#include <math.h>

#define BB 2048
#define CC 10
#define HH 48
#define WW 48
#define HWSZ (HH * WW)      // 2304
#define HW4 (HWSZ / 4)      // 576
#define NTHREADS 256

__device__ __forceinline__ float wave_sum_f(float v) {
    #pragma unroll
    for (int off = 32; off > 0; off >>= 1) v += __shfl_down(v, off, 64);
    return v;
}
__device__ __forceinline__ int wave_sum_i(int v) {
    #pragma unroll
    for (int off = 32; off > 0; off >>= 1) v += __shfl_down(v, off, 64);
    return v;
}
__device__ __forceinline__ int wave_or_i(int v) {
    #pragma unroll
    for (int off = 32; off > 0; off >>= 1) v |= __shfl_down(v, off, 64);
    return v;
}

// One block per batch element.
__global__ __launch_bounds__(NTHREADS) void per_batch_kernel(
    const float* __restrict__ pred,      // [B,C,H,W]
    const float* __restrict__ sfeat,     // [B,256]
    const int*   __restrict__ targets,   // [B,H,W]
    const int*   __restrict__ inputs,    // [B,H,W]
    float* __restrict__ focal_ws,        // [B] sum((1-pt)^g * ce) * w[b]
    float* __restrict__ ultra_teal_o,    // [B]
    float* __restrict__ copy_o,          // [B]
    float* __restrict__ sf_sum_o)        // [B] sum of strategic_features row
{
    __shared__ int tgt[HWSZ];
    __shared__ float rf[4][4];
    __shared__ int ri[4][4];

    const int b = blockIdx.x;
    const int tid = threadIdx.x;

    const float4* __restrict__ pb4 = (const float4*)(pred + (size_t)b * CC * HWSZ);
    const int4*   __restrict__ tb4 = (const int4*)(targets + (size_t)b * HWSZ);
    const int4*   __restrict__ ib4 = (const int4*)(inputs + (size_t)b * HWSZ);

    // stage targets into LDS (vectorized)
    for (int g = tid; g < HW4; g += NTHREADS) {
        ((int4*)tgt)[g] = tb4[g];
    }
    __syncthreads();

    float focal_f = 0.f, iou_f = 0.f, sw_f = 0.f;
    int eq_cnt = 0, copy_cnt = 0, trans_cnt = 0, mask = 0;

    // spatial weight: 1.3 - 0.3 * dist / sqrt(24^2+24^2)
    const float sw_scale = 0.3f / 33.9411254969543f;

    for (int g = tid; g < HW4; g += NTHREADS) {
        // load 10 channels x 4 pixels
        float chv[CC][4];
        #pragma unroll
        for (int c = 0; c < CC; ++c) {
            float4 v = pb4[c * HW4 + g];
            chv[c][0] = v.x; chv[c][1] = v.y; chv[c][2] = v.z; chv[c][3] = v.w;
        }
        int4 t4 = ((const int4*)tgt)[g];
        int4 i4 = ib4[g];
        int tj[4] = {t4.x, t4.y, t4.z, t4.w};
        int ij[4] = {i4.x, i4.y, i4.z, i4.w};

        const int y  = g / (WW / 4);
        const int x0 = (g % (WW / 4)) * 4;
        const int p0 = y * WW + x0;
        const float dy = (float)(y - 24);
        const float dy2 = dy * dy;

        #pragma unroll
        for (int j = 0; j < 4; ++j) {
            const int t = tj[j];
            mask |= (1 << t);
            const int x = x0 + j;
            // transitions (each pair counted once, by its left/top pixel)
            if (x < WW - 1) trans_cnt += (t != tgt[p0 + j + 1]);
            if (y < HH - 1) trans_cnt += (t != tgt[p0 + j + WW]);

            // max / argmax / value-at-target over C=10
            float m = chv[0][j];
            int am = 0;
            float vt = (t == 0) ? chv[0][j] : 0.f;
            #pragma unroll
            for (int c = 1; c < CC; ++c) {
                float vv = chv[c][j];
                if (vv > m) { m = vv; am = c; }
                if (c == t) vt = vv;
            }
            float s = 0.f;
            #pragma unroll
            for (int c = 0; c < CC; ++c) s += __expf(chv[c][j] - m);
            const float lse = m + __logf(s);
            const float logpt = vt - lse;          // log-softmax at target (<= 0)
            const float ce = -logpt;
            const float pt = __expf(logpt);
            const float om = fmaxf(1.f - pt, 0.f);
            focal_f += __powf(om, 2.5f) * ce;

            const bool e = (am == t);
            eq_cnt  += e;
            copy_cnt += (am == ij[j]);
            const float dx = (float)(x - 24);
            const float sw = 1.3f - sw_scale * __fsqrt_rn(dy2 + dx * dx);
            sw_f += sw;
            if (e) iou_f += sw;
        }
    }

    // strategic_features row sum: one element per thread (256 == row length)
    float sf = sfeat[(size_t)b * 256 + tid];

    // reductions
    focal_f = wave_sum_f(focal_f);
    iou_f   = wave_sum_f(iou_f);
    sw_f    = wave_sum_f(sw_f);
    sf      = wave_sum_f(sf);
    eq_cnt  = wave_sum_i(eq_cnt);
    copy_cnt= wave_sum_i(copy_cnt);
    trans_cnt = wave_sum_i(trans_cnt);
    mask    = wave_or_i(mask);

    const int wv = tid >> 6;
    if ((tid & 63) == 0) {
        rf[0][wv] = focal_f; rf[1][wv] = iou_f; rf[2][wv] = sw_f; rf[3][wv] = sf;
        ri[0][wv] = eq_cnt;  ri[1][wv] = copy_cnt; ri[2][wv] = trans_cnt; ri[3][wv] = mask;
    }
    __syncthreads();
    if (tid == 0) {
        float F = 0.f, I = 0.f, S = 0.f, SF = 0.f;
        int EQ = 0, CP = 0, TR = 0, MK = 0;
        #pragma unroll
        for (int i = 0; i < 4; ++i) {
            F += rf[0][i]; I += rf[1][i]; S += rf[2][i]; SF += rf[3][i];
            EQ += ri[0][i]; CP += ri[1][i]; TR += ri[2][i]; MK |= ri[3][i];
        }
        const int uniq = __popc(MK);
        const float w = ((uniq > 4) ? 1.3f : 1.0f) * ((TR > WW) ? 1.2f : 1.0f);
        const float strict = (EQ == HWSZ) ? 1.f : 0.f;
        const float ut = 0.85f * (I / S) + 0.15f * strict;
        focal_ws[b]    = F * w;
        ultra_teal_o[b] = ut;
        copy_o[b]      = (CP == HWSZ) ? 1.f : 0.f;
        sf_sum_o[b]    = SF;
    }
}

__global__ __launch_bounds__(NTHREADS) void finalize_kernel(
    const float* __restrict__ focal_ws,
    const float* __restrict__ ultra_teal,
    const float* __restrict__ copy_v,
    const float* __restrict__ sf_sum,
    const float* __restrict__ planning,
    const float* __restrict__ reasoning,
    float* __restrict__ out)
{
    __shared__ float rf[6][4];
    const int tid = threadIdx.x;
    float f = 0.f, u = 0.f, c = 0.f, s = 0.f, p = 0.f, r = 0.f;
    for (int i = tid; i < BB; i += NTHREADS) {
        f += focal_ws[i];
        u += ultra_teal[i];
        c += copy_v[i];
        s += sf_sum[i];
        p += planning[i];
        r += reasoning[i];
    }
    f = wave_sum_f(f); u = wave_sum_f(u); c = wave_sum_f(c);
    s = wave_sum_f(s); p = wave_sum_f(p); r = wave_sum_f(r);
    const int wv = tid >> 6;
    if ((tid & 63) == 0) {
        rf[0][wv] = f; rf[1][wv] = u; rf[2][wv] = c;
        rf[3][wv] = s; rf[4][wv] = p; rf[5][wv] = r;
    }
    __syncthreads();
    if (tid == 0) {
        float F = 0.f, U = 0.f, Cv = 0.f, S = 0.f, P = 0.f, R = 0.f;
        #pragma unroll
        for (int i = 0; i < 4; ++i) {
            F += rf[0][i]; U += rf[1][i]; Cv += rf[2][i];
            S += rf[3][i]; P += rf[4][i]; R += rf[5][i];
        }
        const float focal = F / (float)(BB * HWSZ);
        const float ut_mean = U / (float)BB;
        const float exact_bonus = fmaxf(-ut_mean * 5.0f, -5.0f);
        const float transform_penalty = (Cv / (float)BB) * 0.5f;
        const float sf_mean = S / (float)(BB * 256);
        const float creativity = (1.0f / (1.0f + __expf(-sf_mean))) * 0.1f;
        const float strategic = (P / (float)BB) * 0.1f;
        const float multi = (R / (float)BB) * 0.1f;
        const float complexity = ut_mean * ((float)HWSZ / 1225.0f) * 0.1f;
        float total = focal + transform_penalty + exact_bonus
                    - creativity - strategic - multi - complexity;
        if (isnan(total) || isinf(total)) total = fminf(focal, 10.0f);
        out[0] = total;
    }
}

extern "C" void kernel_launch(void* const* d_in, const int* in_sizes, int n_in,
                              void* d_out, int out_size, void* d_ws, size_t ws_size,
                              hipStream_t stream) {
    const float* pred      = (const float*)d_in[0];
    const float* sfeat     = (const float*)d_in[1];
    const float* planning  = (const float*)d_in[2];
    const float* reasoning = (const float*)d_in[3];
    const int*   targets   = (const int*)d_in[4];
    const int*   inputs    = (const int*)d_in[5];
    float* out = (float*)d_out;

    float* ws = (float*)d_ws;
    float* focal_ws   = ws;
    float* ultra_teal = ws + BB;
    float* copy_v     = ws + 2 * BB;
    float* sf_sum     = ws + 3 * BB;

    per_batch_kernel<<<BB, NTHREADS, 0, stream>>>(
        pred, sfeat, targets, inputs, focal_ws, ultra_teal, copy_v, sf_sum);
    finalize_kernel<<<1, NTHREADS, 0, stream>>>(
        focal_ws, ultra_teal, copy_v, sf_sum, planning, reasoning, out);
}

// Round 2
// 296.838 us; speedup vs baseline: 1.0232x; 1.0232x over previous
//
#include <hip/hip_runtime.h>
#include <math.h>

#define BB 2048
#define CC 10
#define HH 48
#define WW 48
#define HWSZ (HH * WW)      // 2304
#define HW2 (HWSZ / 2)      // 1152
#define NT 384              // 6 waves; HW2/NT == 3 exact iterations
#define NITER (HW2 / NT)    // 3
#define NWAVE (NT / 64)     // 6

__device__ __forceinline__ float wave_sum_f(float v) {
    #pragma unroll
    for (int off = 32; off > 0; off >>= 1) v += __shfl_down(v, off, 64);
    return v;
}
__device__ __forceinline__ int wave_sum_i(int v) {
    #pragma unroll
    for (int off = 32; off > 0; off >>= 1) v += __shfl_down(v, off, 64);
    return v;
}
__device__ __forceinline__ int wave_or_i(int v) {
    #pragma unroll
    for (int off = 32; off > 0; off >>= 1) v |= __shfl_down(v, off, 64);
    return v;
}

// One block per batch element. 384 threads, 2 pixels/thread/iter, 3 iters.
__global__ __launch_bounds__(NT, 4) void per_batch_kernel(
    const float* __restrict__ pred,      // [B,C,H,W]
    const float* __restrict__ sfeat,     // [B,256]
    const int*   __restrict__ targets,   // [B,H,W]
    const int*   __restrict__ inputs,    // [B,H,W]
    float* __restrict__ focal_ws,        // [B]
    float* __restrict__ ultra_teal_o,    // [B]
    float* __restrict__ copy_o,          // [B]
    float* __restrict__ sf_sum_o)        // [B]
{
    __shared__ int   tgt[HWSZ];
    __shared__ float swt[HWSZ];
    __shared__ float rf[4][NWAVE];
    __shared__ int   ri[4][NWAVE];

    const int b = blockIdx.x;
    const int tid = threadIdx.x;

    const float2* __restrict__ pb2 = (const float2*)(pred + (size_t)b * CC * HWSZ);
    const int2*   __restrict__ tb2 = (const int2*)(targets + (size_t)b * HWSZ);
    const int2*   __restrict__ ib2 = (const int2*)(inputs + (size_t)b * HWSZ);

    // preload own targets/inputs (registers), stage targets into LDS
    int2 treg[NITER], ireg[NITER];
    #pragma unroll
    for (int k = 0; k < NITER; ++k) {
        const int g = tid + k * NT;
        treg[k] = tb2[g];
        ireg[k] = ib2[g];
        ((int2*)tgt)[g] = treg[k];
    }
    // spatial-weight table: 1.3 - (0.3/33.941125) * dist   (6 entries/thread)
    const float sw_scale = 0.3f / 33.9411254969543f;
    #pragma unroll
    for (int k = 0; k < HWSZ / NT; ++k) {
        const int s = tid + k * NT;
        const int y = s / WW;
        const int x = s - y * WW;
        const float dy = (float)(y - 24);
        const float dx = (float)(x - 24);
        swt[s] = 1.3f - sw_scale * __fsqrt_rn(dy * dy + dx * dx);
    }
    __syncthreads();

    float focal_f = 0.f, iou_f = 0.f, swsum_f = 0.f;
    int eq_cnt = 0, copy_cnt = 0, trans_cnt = 0, mask = 0;

    #pragma unroll
    for (int k = 0; k < NITER; ++k) {
        const int g = tid + k * NT;
        // 10 channels x 2 pixels
        float2 v[CC];
        #pragma unroll
        for (int c = 0; c < CC; ++c) v[c] = pb2[c * HW2 + g];

        const int2 t2 = treg[k];
        const int2 i2 = ireg[k];
        const int p0 = 2 * g;
        const int y  = g / (WW / 2);
        const int x0 = (g - y * (WW / 2)) * 2;

        // transitions
        int th = (t2.x != t2.y);
        if (x0 < WW - 2) th += (t2.y != tgt[p0 + 2]);
        if (y < HH - 1) {
            const int2 bl = ((const int2*)tgt)[g + WW / 2];
            th += (t2.x != bl.x) + (t2.y != bl.y);
        }
        trans_cnt += th;
        mask |= (1 << t2.x) | (1 << t2.y);

        // max/argmax/value-at-target over C=10, both pixels
        float m0 = v[0].x, m1 = v[0].y;
        int a0 = 0, a1 = 0;
        float vt0 = (t2.x == 0) ? v[0].x : 0.f;
        float vt1 = (t2.y == 0) ? v[0].y : 0.f;
        #pragma unroll
        for (int c = 1; c < CC; ++c) {
            const float vx = v[c].x, vy = v[c].y;
            if (vx > m0) { m0 = vx; a0 = c; }
            if (vy > m1) { m1 = vy; a1 = c; }
            if (c == t2.x) vt0 = vx;
            if (c == t2.y) vt1 = vy;
        }
        float s0 = 0.f, s1 = 0.f;
        #pragma unroll
        for (int c = 0; c < CC; ++c) {
            s0 += __expf(v[c].x - m0);
            s1 += __expf(v[c].y - m1);
        }
        const float lse0 = m0 + __logf(s0);
        const float lse1 = m1 + __logf(s1);
        const float ce0 = lse0 - vt0;
        const float ce1 = lse1 - vt1;
        const float pt0 = __expf(vt0 - lse0);
        const float pt1 = __expf(vt1 - lse1);
        const float om0 = fmaxf(1.f - pt0, 0.f);
        const float om1 = fmaxf(1.f - pt1, 0.f);
        // om^2.5 = om^2 * sqrt(om)
        focal_f += om0 * om0 * __fsqrt_rn(om0) * ce0
                 + om1 * om1 * __fsqrt_rn(om1) * ce1;

        eq_cnt   += (a0 == t2.x) + (a1 == t2.y);
        copy_cnt += (a0 == i2.x) + (a1 == i2.y);

        const float2 swp = ((const float2*)swt)[g];
        swsum_f += swp.x + swp.y;
        iou_f   += ((a0 == t2.x) ? swp.x : 0.f) + ((a1 == t2.y) ? swp.y : 0.f);
    }

    // strategic_features row sum (256 elements, first 256 threads)
    float sf = (tid < 256) ? sfeat[(size_t)b * 256 + tid] : 0.f;

    focal_f  = wave_sum_f(focal_f);
    iou_f    = wave_sum_f(iou_f);
    swsum_f  = wave_sum_f(swsum_f);
    sf       = wave_sum_f(sf);
    eq_cnt   = wave_sum_i(eq_cnt);
    copy_cnt = wave_sum_i(copy_cnt);
    trans_cnt = wave_sum_i(trans_cnt);
    mask     = wave_or_i(mask);

    const int wv = tid >> 6;
    if ((tid & 63) == 0) {
        rf[0][wv] = focal_f; rf[1][wv] = iou_f; rf[2][wv] = swsum_f; rf[3][wv] = sf;
        ri[0][wv] = eq_cnt;  ri[1][wv] = copy_cnt; ri[2][wv] = trans_cnt; ri[3][wv] = mask;
    }
    __syncthreads();
    if (tid == 0) {
        float F = 0.f, I = 0.f, S = 0.f, SF = 0.f;
        int EQ = 0, CP = 0, TR = 0, MK = 0;
        #pragma unroll
        for (int i = 0; i < NWAVE; ++i) {
            F += rf[0][i]; I += rf[1][i]; S += rf[2][i]; SF += rf[3][i];
            EQ += ri[0][i]; CP += ri[1][i]; TR += ri[2][i]; MK |= ri[3][i];
        }
        const int uniq = __popc(MK);
        const float w = ((uniq > 4) ? 1.3f : 1.0f) * ((TR > WW) ? 1.2f : 1.0f);
        const float strict = (EQ == HWSZ) ? 1.f : 0.f;
        const float ut = 0.85f * (I / S) + 0.15f * strict;
        focal_ws[b]     = F * w;
        ultra_teal_o[b] = ut;
        copy_o[b]       = (CP == HWSZ) ? 1.f : 0.f;
        sf_sum_o[b]     = SF;
    }
}

__global__ __launch_bounds__(256) void finalize_kernel(
    const float* __restrict__ focal_ws,
    const float* __restrict__ ultra_teal,
    const float* __restrict__ copy_v,
    const float* __restrict__ sf_sum,
    const float* __restrict__ planning,
    const float* __restrict__ reasoning,
    float* __restrict__ out)
{
    __shared__ float rf[6][4];
    const int tid = threadIdx.x;
    float f = 0.f, u = 0.f, c = 0.f, s = 0.f, p = 0.f, r = 0.f;
    for (int i = tid; i < BB; i += 256) {
        f += focal_ws[i];
        u += ultra_teal[i];
        c += copy_v[i];
        s += sf_sum[i];
        p += planning[i];
        r += reasoning[i];
    }
    f = wave_sum_f(f); u = wave_sum_f(u); c = wave_sum_f(c);
    s = wave_sum_f(s); p = wave_sum_f(p); r = wave_sum_f(r);
    const int wv = tid >> 6;
    if ((tid & 63) == 0) {
        rf[0][wv] = f; rf[1][wv] = u; rf[2][wv] = c;
        rf[3][wv] = s; rf[4][wv] = p; rf[5][wv] = r;
    }
    __syncthreads();
    if (tid == 0) {
        float F = 0.f, U = 0.f, Cv = 0.f, S = 0.f, P = 0.f, R = 0.f;
        #pragma unroll
        for (int i = 0; i < 4; ++i) {
            F += rf[0][i]; U += rf[1][i]; Cv += rf[2][i];
            S += rf[3][i]; P += rf[4][i]; R += rf[5][i];
        }
        const float focal = F / (float)(BB * HWSZ);
        const float ut_mean = U / (float)BB;
        const float exact_bonus = fmaxf(-ut_mean * 5.0f, -5.0f);
        const float transform_penalty = (Cv / (float)BB) * 0.5f;
        const float sf_mean = S / (float)(BB * 256);
        const float creativity = (1.0f / (1.0f + __expf(-sf_mean))) * 0.1f;
        const float strategic = (P / (float)BB) * 0.1f;
        const float multi = (R / (float)BB) * 0.1f;
        const float complexity = ut_mean * ((float)HWSZ / 1225.0f) * 0.1f;
        float total = focal + transform_penalty + exact_bonus
                    - creativity - strategic - multi - complexity;
        if (isnan(total) || isinf(total)) total = fminf(focal, 10.0f);
        out[0] = total;
    }
}

extern "C" void kernel_launch(void* const* d_in, const int* in_sizes, int n_in,
                              void* d_out, int out_size, void* d_ws, size_t ws_size,
                              hipStream_t stream) {
    const float* pred      = (const float*)d_in[0];
    const float* sfeat     = (const float*)d_in[1];
    const float* planning  = (const float*)d_in[2];
    const float* reasoning = (const float*)d_in[3];
    const int*   targets   = (const int*)d_in[4];
    const int*   inputs    = (const int*)d_in[5];
    float* out = (float*)d_out;

    float* ws = (float*)d_ws;
    float* focal_ws   = ws;
    float* ultra_teal = ws + BB;
    float* copy_v     = ws + 2 * BB;
    float* sf_sum     = ws + 3 * BB;

    per_batch_kernel<<<BB, NT, 0, stream>>>(
        pred, sfeat, targets, inputs, focal_ws, ultra_teal, copy_v, sf_sum);
    finalize_kernel<<<1, 256, 0, stream>>>(
        focal_ws, ultra_teal, copy_v, sf_sum, planning, reasoning, out);
}